// Round 12
// baseline (54.493 us; speedup 1.0000x reference)
//
#include <hip/hip_runtime.h>
#include <math.h>

#define BB 4
#define NN 16384
#define CC 128
#define MM 128
#define SS 512
#define OUT_ROW 131                    // 3 coords + 128 features
#define NSEG 256                       // 16384 / 64 segments per box
#define ELEMS_PER_BOX (SS * OUT_ROW)   // 67072
#define G2 16                          // row-groups per box (32 rows each)
#define QPB 1048                       // quads per block (32*131/4)

typedef float f32x4 __attribute__((ext_vector_type(4)));

// ---------------- K1: per-box stable in-box index selection ----------------
// 512 blocks (one per box) x 512 threads (8 waves).
// Emits ws_idx[bm][0..SS) with the row%cnt wrap ALREADY applied.
__global__ __launch_bounds__(512) void k1_select(
    const float* __restrict__ points,   // (B, N, 3)
    const float* __restrict__ boxes,    // (B, M, 7)
    int* __restrict__ ws_idx,           // (B*M, SS)
    int* __restrict__ ws_cnt,           // (B*M)
    float* __restrict__ out_flag)       // (B*M) as float 0/1
{
    const int bm   = blockIdx.x;
    const int b    = bm >> 7;
    const int m    = bm & (MM - 1);
    const int tid  = threadIdx.x;
    const int lane = tid & 63;
    const int wave = tid >> 6;

    __shared__ unsigned long long s_mask[NSEG];
    __shared__ int s_wsum[4];

    // box params, enlarged: cz -= 0.5, d* += 1.0
    const float* bx = boxes + (size_t)(b * MM + m) * 7;
    const float cx  = bx[0];
    const float cy  = bx[1];
    const float cz  = __fadd_rn(bx[2], -0.5f);
    const float hx  = __fmul_rn(__fadd_rn(bx[3], 1.0f), 0.5f);
    const float hy  = __fmul_rn(__fadd_rn(bx[4], 1.0f), 0.5f);
    const float hz  = __fmul_rn(__fadd_rn(bx[5], 1.0f), 0.5f);
    const float yaw = bx[6];
    const float cosa = (float)cos((double)yaw);
    const float sina = (float)sin((double)yaw);
    const float zc   = __fadd_rn(cz, hz);

    const float* pbase = points + (size_t)b * NN * 3;

    // ---- Pass A: wave w handles segments [w*32, w*32+32) ----
    #pragma unroll 4
    for (int k = 0; k < 32; ++k) {
        const int s = wave * 32 + k;
        const int i = s * 64 + lane;
        const float px = pbase[i * 3 + 0];
        const float py = pbase[i * 3 + 1];
        const float pz = pbase[i * 3 + 2];
        const float sx = __fadd_rn(px, -cx);
        const float sy = __fadd_rn(py, -cy);
        const float lx = __fadd_rn(__fmul_rn(sx, cosa), __fmul_rn(sy, sina));
        const float ly = __fadd_rn(__fmul_rn(-sx, sina), __fmul_rn(sy, cosa));
        const bool in_box = (fabsf(lx) < hx) & (fabsf(ly) < hy) &
                            (fabsf(__fadd_rn(pz, -zc)) <= hz);
        const unsigned long long mask = __ballot(in_box);
        if (lane == 0) s_mask[s] = mask;
    }
    __syncthreads();

    // ---- Pass B: prefix scan over 256 segment counts (threads 0..255) ----
    unsigned long long mymask = 0ull;
    int c = 0;
    if (tid < NSEG) {
        mymask = s_mask[tid];
        c = __popcll(mymask);
    }
    int inc = c;
    #pragma unroll
    for (int d = 1; d < 64; d <<= 1) {
        int v = __shfl_up(inc, d);
        if (lane >= d) inc += v;
    }
    if (tid < NSEG && lane == 63) s_wsum[wave] = inc;
    __syncthreads();

    int woff = 0, total = 0;
    #pragma unroll
    for (int w = 0; w < 4; ++w) {
        const int v = s_wsum[w];
        if (w < wave) woff += v;
        total += v;
    }

    int* dst = ws_idx + (size_t)bm * SS;

    // ---- Pass C: emit indices (stable ascending order), first SS only ----
    if (tid < NSEG) {
        int base = woff + inc - c;          // exclusive prefix
        if (base < SS) {
            unsigned long long mk = mymask;
            while (mk) {
                const int bit = __ffsll(mk) - 1;
                mk &= mk - 1;
                dst[base] = tid * 64 + bit;
                if (++base >= SS) break;
            }
        }
    }
    __syncthreads();

    // ---- Pass D: expand with row % cnt wrap so K2 needs no division ----
    const int cnt = total;
    if (cnt > 0) {
        for (int row = cnt + tid; row < SS; row += 512)
            dst[row] = dst[row % cnt];
    }
    if (tid == 0) {
        ws_cnt[bm] = cnt;
        out_flag[bm] = (cnt == 0) ? 1.0f : 0.0f;
    }
}

// ---------------- K2: direct gather -> CACHED store (A/B vs R11's NT) ----------------
// Identical to R11 except stores go through L2 (no nontemporal hint).
__global__ __launch_bounds__(256) void k2_gather(
    const float* __restrict__ points,
    const float* __restrict__ feats,    // (B, N, C)
    const int* __restrict__ ws_idx,
    const int* __restrict__ ws_cnt,
    float* __restrict__ out_feat)       // (B, M, S, 131)
{
    const int orig = blockIdx.x;
    const int blk  = ((orig & 7) << 10) | (orig >> 3);   // 8192 = 8 XCD x 1024
    const int bm   = blk >> 4;
    const int g    = blk & (G2 - 1);
    const int row0 = g << 5;
    const int tid  = threadIdx.x;

    const int cnt = ws_cnt[bm];
    // block's output region: 32 rows = 1048 quads, 16B-aligned (4192 % 4 == 0)
    f32x4* oq = (f32x4*)(out_feat + (size_t)bm * ELEMS_PER_BOX
                                  + (size_t)row0 * OUT_ROW);

    if (cnt == 0) {
        const f32x4 z = (f32x4)0.0f;
        #pragma unroll
        for (int it = 0; it < 5; ++it) {
            const int e4 = tid + it * 256;
            if (it == 4 && tid >= QPB - 1024) continue;
            oq[e4] = z;
        }
        return;
    }

    __shared__ int s_pi[33];            // 32 rows + 1 for row-crossing quads
    if (tid < 33) {
        int r = row0 + tid; if (r > SS - 1) r = SS - 1;  // clamp (never used)
        s_pi[tid] = ws_idx[(size_t)bm * SS + r];
    }
    __syncthreads();

    const int b = bm >> 7;
    const float* pb = points + (size_t)b * NN * 3;
    const float* fb = feats + (size_t)b * NN * CC;

    f32x4 vv[5];
    // phase 1: gather all quads into registers (independent loads in flight)
    #pragma unroll
    for (int it = 0; it < 5; ++it) {
        const int e4 = tid + it * 256;
        if (it == 4 && tid >= QPB - 1024) continue;
        const int e   = e4 * 4;
        const int rl  = e / 131;                 // magic-mul const div
        const int col = e - rl * 131;
        if (col >= 3 && col <= 127) {
            const int pi = s_pi[rl];
            f32x4 v;
            __builtin_memcpy(&v, fb + (size_t)pi * CC + (col - 3), 16);
            vv[it] = v;
        } else {
            f32x4 v;
            #pragma unroll
            for (int j = 0; j < 4; ++j) {
                const int gg    = col + j;
                const int cross = (gg >= OUT_ROW) ? 1 : 0;
                const int rl2   = rl + cross;
                const int c2    = gg - cross * OUT_ROW;
                const int pi2   = s_pi[rl2];
                v[j] = (c2 < 3) ? pb[pi2 * 3 + c2]
                                : fb[(size_t)pi2 * CC + (c2 - 3)];
            }
            vv[it] = v;
        }
    }
    // phase 2: stream out (aligned cached dwordx4)
    #pragma unroll
    for (int it = 0; it < 5; ++it) {
        const int e4 = tid + it * 256;
        if (it == 4 && tid >= QPB - 1024) continue;
        oq[e4] = vv[it];
    }
}

extern "C" void kernel_launch(void* const* d_in, const int* in_sizes, int n_in,
                              void* d_out, int out_size, void* d_ws, size_t ws_size,
                              hipStream_t stream) {
    const float* points = (const float*)d_in[0];
    const float* feats  = (const float*)d_in[1];
    const float* boxes  = (const float*)d_in[2];
    float* out_feat = (float*)d_out;
    float* out_flag = (float*)d_out + (size_t)BB * MM * SS * OUT_ROW;

    int* ws_idx = (int*)d_ws;                       // 512*512 ints = 1 MB
    int* ws_cnt = ws_idx + (size_t)BB * MM * SS;    // 512 ints

    k1_select<<<BB * MM, 512, 0, stream>>>(points, boxes, ws_idx, ws_cnt, out_flag);
    k2_gather<<<BB * MM * G2, 256, 0, stream>>>(points, feats, ws_idx, ws_cnt, out_feat);
}

// Round 13
// 44.362 us; speedup vs baseline: 1.2284x; 1.2284x over previous
//
#include <hip/hip_runtime.h>
#include <math.h>

#define BB 4
#define NN 16384
#define CC 128
#define MM 128
#define SS 512
#define OUT_ROW 131                    // 3 coords + 128 features
#define NSEG 256                       // 16384 / 64 segments per box
#define ELEMS_PER_BOX (SS * OUT_ROW)   // 67072
#define QPH 8384                       // quads per half-box (256*131/4)

typedef float f32x4 __attribute__((ext_vector_type(4)));

// ---------------- Fused select + gather ----------------
// 1024 blocks x 512 threads: 2 blocks per box (halves), 4 blocks/CU.
// Phase 1 (both half-blocks, redundant): ballot-scan of all 16384 points,
//   prefix over 256 segment masks, stable emit of first 512 indices + wrap
//   expansion — all in LDS (no workspace round-trip).
// Phase 2: half-box gather (8384 quads): fast path = one f32x4 feature load +
//   one aligned NT dwordx4 store; special quads (coords/row-cross) scalar.
// Bijective XCD swizzle: 64 consecutive boxes per XCD.
__global__ __launch_bounds__(512, 8) void roipool_fused(
    const float* __restrict__ points,   // (B, N, 3)
    const float* __restrict__ feats,    // (B, N, C)
    const float* __restrict__ boxes,    // (B, M, 7)
    float* __restrict__ out_feat,       // (B, M, S, 131)
    float* __restrict__ out_flag)       // (B*M) as float 0/1
{
    const int orig = blockIdx.x;
    const int blk  = ((orig & 7) << 7) | (orig >> 3);   // 1024 = 8 XCD x 128
    const int bm   = blk >> 1;
    const int g    = blk & 1;           // which half of the box
    const int b    = bm >> 7;
    const int m    = bm & (MM - 1);
    const int tid  = threadIdx.x;
    const int lane = tid & 63;
    const int wave = tid >> 6;

    __shared__ unsigned long long s_mask[NSEG];
    __shared__ int s_wsum[4];
    __shared__ int s_idx[SS];

    // ---- box params, enlarged: cz -= 0.5, d* += 1.0 ----
    const float* bx = boxes + (size_t)(b * MM + m) * 7;
    const float cx  = bx[0];
    const float cy  = bx[1];
    const float cz  = __fadd_rn(bx[2], -0.5f);
    const float hx  = __fmul_rn(__fadd_rn(bx[3], 1.0f), 0.5f);
    const float hy  = __fmul_rn(__fadd_rn(bx[4], 1.0f), 0.5f);
    const float hz  = __fmul_rn(__fadd_rn(bx[5], 1.0f), 0.5f);
    const float yaw = bx[6];
    const float cosa = (float)cos((double)yaw);
    const float sina = (float)sin((double)yaw);
    const float zc   = __fadd_rn(cz, hz);

    const float* pb = points + (size_t)b * NN * 3;
    const float* fb = feats + (size_t)b * NN * CC;

    // ---- Pass A: wave w ballots segments [w*32, w*32+32) ----
    #pragma unroll 4
    for (int k = 0; k < 32; ++k) {
        const int s = wave * 32 + k;
        const int i = s * 64 + lane;
        const float px = pb[i * 3 + 0];
        const float py = pb[i * 3 + 1];
        const float pz = pb[i * 3 + 2];
        const float sx = __fadd_rn(px, -cx);
        const float sy = __fadd_rn(py, -cy);
        const float lx = __fadd_rn(__fmul_rn(sx, cosa), __fmul_rn(sy, sina));
        const float ly = __fadd_rn(__fmul_rn(-sx, sina), __fmul_rn(sy, cosa));
        const bool in_box = (fabsf(lx) < hx) & (fabsf(ly) < hy) &
                            (fabsf(__fadd_rn(pz, -zc)) <= hz);
        const unsigned long long mask = __ballot(in_box);
        if (lane == 0) s_mask[s] = mask;
    }
    __syncthreads();

    // ---- Pass B: prefix scan over 256 segment counts (threads 0..255) ----
    unsigned long long mymask = 0ull;
    int c = 0;
    if (tid < NSEG) {
        mymask = s_mask[tid];
        c = __popcll(mymask);
    }
    int inc = c;
    #pragma unroll
    for (int d = 1; d < 64; d <<= 1) {
        int v = __shfl_up(inc, d);
        if (lane >= d) inc += v;
    }
    if (tid < NSEG && lane == 63) s_wsum[wave] = inc;
    __syncthreads();

    int woff = 0, total = 0;
    #pragma unroll
    for (int w = 0; w < 4; ++w) {
        const int v = s_wsum[w];
        if (w < wave) woff += v;
        total += v;
    }
    const int cnt = total;

    // output region for this half-box: 8384 quads, 16B-aligned
    f32x4* oq = (f32x4*)out_feat + (size_t)bm * (ELEMS_PER_BOX / 4)
              + (size_t)g * QPH;

    if (cnt == 0) {
        if (g == 0 && tid == 0) out_flag[bm] = 1.0f;
        const f32x4 z = (f32x4)0.0f;
        #pragma unroll
        for (int it = 0; it < 16; ++it)
            __builtin_nontemporal_store(z, oq + it * 512 + tid);
        if (tid < QPH - 8192)
            __builtin_nontemporal_store(z, oq + 8192 + tid);
        return;
    }
    if (g == 0 && tid == 0) out_flag[bm] = 0.0f;

    // ---- Pass C: stable emit of first SS indices into LDS ----
    if (tid < NSEG) {
        int base = woff + inc - c;          // exclusive prefix
        if (base < SS) {
            unsigned long long mk = mymask;
            while (mk) {
                const int bit = __ffsll(mk) - 1;
                mk &= mk - 1;
                s_idx[base] = tid * 64 + bit;
                if (++base >= SS) break;
            }
        }
    }
    __syncthreads();

    // ---- Pass D: wrap expansion (row % cnt) in LDS ----
    if (cnt < SS) {
        for (int row = cnt + tid; row < SS; row += 512)
            s_idx[row] = s_idx[row % cnt];
    }
    __syncthreads();

    // ---- Phase 2: gather this half-box ----
    const int ebase = g * (QPH * 4);        // element offset within box

    #pragma unroll
    for (int bt = 0; bt < 4; ++bt) {
        f32x4 vv[4];
        // load batch (4 independent quads in flight)
        #pragma unroll
        for (int j = 0; j < 4; ++j) {
            const int e4 = (bt * 4 + j) * 512 + tid;
            const int e  = ebase + e4 * 4;
            const int rl  = e / 131;
            const int col = e - rl * 131;
            if (col >= 3 && col <= 127) {
                const int pi = s_idx[rl];
                f32x4 v;
                __builtin_memcpy(&v, fb + (size_t)pi * CC + (col - 3), 16);
                vv[j] = v;
            } else {
                f32x4 v;
                #pragma unroll
                for (int jj = 0; jj < 4; ++jj) {
                    const int gg    = col + jj;
                    const int cross = (gg >= OUT_ROW) ? 1 : 0;
                    const int rl2   = rl + cross;
                    const int c2    = gg - cross * OUT_ROW;
                    const int pi2   = s_idx[rl2];
                    v[jj] = (c2 < 3) ? pb[pi2 * 3 + c2]
                                     : fb[(size_t)pi2 * CC + (c2 - 3)];
                }
                vv[j] = v;
            }
        }
        // store batch
        #pragma unroll
        for (int j = 0; j < 4; ++j)
            __builtin_nontemporal_store(vv[j], oq + (bt * 4 + j) * 512 + tid);
    }
    // tail: 192 quads
    if (tid < QPH - 8192) {
        const int e4 = 8192 + tid;
        const int e  = ebase + e4 * 4;
        const int rl  = e / 131;
        const int col = e - rl * 131;
        f32x4 v;
        if (col >= 3 && col <= 127) {
            const int pi = s_idx[rl];
            __builtin_memcpy(&v, fb + (size_t)pi * CC + (col - 3), 16);
        } else {
            #pragma unroll
            for (int jj = 0; jj < 4; ++jj) {
                const int gg    = col + jj;
                const int cross = (gg >= OUT_ROW) ? 1 : 0;
                const int rl2   = rl + cross;
                const int c2    = gg - cross * OUT_ROW;
                const int pi2   = s_idx[rl2];
                v[jj] = (c2 < 3) ? pb[pi2 * 3 + c2]
                                 : fb[(size_t)pi2 * CC + (c2 - 3)];
            }
        }
        __builtin_nontemporal_store(v, oq + e4);
    }
}

extern "C" void kernel_launch(void* const* d_in, const int* in_sizes, int n_in,
                              void* d_out, int out_size, void* d_ws, size_t ws_size,
                              hipStream_t stream) {
    const float* points = (const float*)d_in[0];
    const float* feats  = (const float*)d_in[1];
    const float* boxes  = (const float*)d_in[2];
    float* out_feat = (float*)d_out;
    float* out_flag = (float*)d_out + (size_t)BB * MM * SS * OUT_ROW;

    roipool_fused<<<BB * MM * 2, 512, 0, stream>>>(points, feats, boxes,
                                                   out_feat, out_flag);
}

// Round 14
// 40.412 us; speedup vs baseline: 1.3484x; 1.0978x over previous
//
#include <hip/hip_runtime.h>
#include <math.h>

#define BB 4
#define NN 16384
#define CC 128
#define MM 128
#define SS 512
#define OUT_ROW 131                    // 3 coords + 128 features
#define NSEG 256                       // 16384 / 64 segments per box
#define ELEMS_PER_BOX (SS * OUT_ROW)   // 67072
#define QPBOX (ELEMS_PER_BOX / 4)      // 16768 quads per box

typedef float f32x4 __attribute__((ext_vector_type(4)));

// ---------------- Fused select + gather, one block per box ----------------
// 512 blocks x 1024 threads (16 waves): 2 blocks/CU = 32 waves/CU.
// Selection runs ONCE per box (16 segment-iterations per wave, half of R13's
// serial depth); indices live in LDS; then the block gathers all 16768 quads.
// Fast path = one f32x4 feature load + one aligned NT dwordx4 store.
// Bijective XCD swizzle: 64 consecutive boxes per XCD (512 = 8 x 64).
__global__ __launch_bounds__(1024, 8) void roipool_fused(
    const float* __restrict__ points,   // (B, N, 3)
    const float* __restrict__ feats,    // (B, N, C)
    const float* __restrict__ boxes,    // (B, M, 7)
    float* __restrict__ out_feat,       // (B, M, S, 131)
    float* __restrict__ out_flag)       // (B*M) as float 0/1
{
    const int orig = blockIdx.x;
    const int bm   = ((orig & 7) << 6) | (orig >> 3);   // 512 = 8 XCD x 64
    const int b    = bm >> 7;
    const int m    = bm & (MM - 1);
    const int tid  = threadIdx.x;
    const int lane = tid & 63;
    const int wave = tid >> 6;          // 0..15

    __shared__ unsigned long long s_mask[NSEG];
    __shared__ int s_wsum[4];
    __shared__ int s_idx[SS];

    // ---- box params, enlarged: cz -= 0.5, d* += 1.0 ----
    const float* bx = boxes + (size_t)(b * MM + m) * 7;
    const float cx  = bx[0];
    const float cy  = bx[1];
    const float cz  = __fadd_rn(bx[2], -0.5f);
    const float hx  = __fmul_rn(__fadd_rn(bx[3], 1.0f), 0.5f);
    const float hy  = __fmul_rn(__fadd_rn(bx[4], 1.0f), 0.5f);
    const float hz  = __fmul_rn(__fadd_rn(bx[5], 1.0f), 0.5f);
    const float yaw = bx[6];
    const float cosa = (float)cos((double)yaw);
    const float sina = (float)sin((double)yaw);
    const float zc   = __fadd_rn(cz, hz);

    const float* pb = points + (size_t)b * NN * 3;
    const float* fb = feats + (size_t)b * NN * CC;

    // ---- Pass A: wave w ballots segments [w*16, w*16+16) ----
    #pragma unroll 4
    for (int k = 0; k < 16; ++k) {
        const int s = wave * 16 + k;
        const int i = s * 64 + lane;
        const float px = pb[i * 3 + 0];
        const float py = pb[i * 3 + 1];
        const float pz = pb[i * 3 + 2];
        const float sx = __fadd_rn(px, -cx);
        const float sy = __fadd_rn(py, -cy);
        const float lx = __fadd_rn(__fmul_rn(sx, cosa), __fmul_rn(sy, sina));
        const float ly = __fadd_rn(__fmul_rn(-sx, sina), __fmul_rn(sy, cosa));
        const bool in_box = (fabsf(lx) < hx) & (fabsf(ly) < hy) &
                            (fabsf(__fadd_rn(pz, -zc)) <= hz);
        const unsigned long long mask = __ballot(in_box);
        if (lane == 0) s_mask[s] = mask;
    }
    __syncthreads();

    // ---- Pass B: prefix scan over 256 segment counts (threads 0..255) ----
    unsigned long long mymask = 0ull;
    int c = 0;
    if (tid < NSEG) {
        mymask = s_mask[tid];
        c = __popcll(mymask);
    }
    int inc = c;
    #pragma unroll
    for (int d = 1; d < 64; d <<= 1) {
        int v = __shfl_up(inc, d);
        if (lane >= d) inc += v;
    }
    if (tid < NSEG && lane == 63) s_wsum[wave] = inc;
    __syncthreads();

    int woff = 0, total = 0;
    #pragma unroll
    for (int w = 0; w < 4; ++w) {
        const int v = s_wsum[w];
        if (w < wave) woff += v;
        total += v;
    }
    const int cnt = total;

    f32x4* oq = (f32x4*)out_feat + (size_t)bm * QPBOX;

    if (cnt == 0) {
        if (tid == 0) out_flag[bm] = 1.0f;
        const f32x4 z = (f32x4)0.0f;
        #pragma unroll
        for (int it = 0; it < 16; ++it)
            __builtin_nontemporal_store(z, oq + it * 1024 + tid);
        if (tid < QPBOX - 16384)
            __builtin_nontemporal_store(z, oq + 16384 + tid);
        return;
    }
    if (tid == 0) out_flag[bm] = 0.0f;

    // ---- Pass C: stable emit of first SS indices into LDS ----
    if (tid < NSEG) {
        int base = woff + inc - c;          // exclusive prefix
        if (base < SS) {
            unsigned long long mk = mymask;
            while (mk) {
                const int bit = __ffsll(mk) - 1;
                mk &= mk - 1;
                s_idx[base] = tid * 64 + bit;
                if (++base >= SS) break;
            }
        }
    }
    __syncthreads();

    // ---- Pass D: wrap expansion (row % cnt) in LDS ----
    if (cnt < SS) {
        for (int row = cnt + tid; row < SS; row += 1024)
            s_idx[row] = s_idx[row % cnt];
    }
    __syncthreads();

    // ---- Phase 2: gather the whole box (16768 quads) ----
    #pragma unroll
    for (int bt = 0; bt < 4; ++bt) {
        f32x4 vv[4];
        // load batch (4 independent quads in flight)
        #pragma unroll
        for (int j = 0; j < 4; ++j) {
            const int e4 = (bt * 4 + j) * 1024 + tid;
            const int e  = e4 * 4;
            const int rl  = e / 131;
            const int col = e - rl * 131;
            if (col >= 3 && col <= 127) {
                const int pi = s_idx[rl];
                f32x4 v;
                __builtin_memcpy(&v, fb + (size_t)pi * CC + (col - 3), 16);
                vv[j] = v;
            } else {
                f32x4 v;
                #pragma unroll
                for (int jj = 0; jj < 4; ++jj) {
                    const int gg    = col + jj;
                    const int cross = (gg >= OUT_ROW) ? 1 : 0;
                    const int rl2   = rl + cross;
                    const int c2    = gg - cross * OUT_ROW;
                    const int pi2   = s_idx[rl2 < SS ? rl2 : SS - 1];
                    v[jj] = (c2 < 3) ? pb[pi2 * 3 + c2]
                                     : fb[(size_t)pi2 * CC + (c2 - 3)];
                }
                vv[j] = v;
            }
        }
        // store batch
        #pragma unroll
        for (int j = 0; j < 4; ++j)
            __builtin_nontemporal_store(vv[j], oq + (bt * 4 + j) * 1024 + tid);
    }
    // tail: 384 quads
    if (tid < QPBOX - 16384) {
        const int e4 = 16384 + tid;
        const int e  = e4 * 4;
        const int rl  = e / 131;
        const int col = e - rl * 131;
        f32x4 v;
        if (col >= 3 && col <= 127) {
            const int pi = s_idx[rl];
            __builtin_memcpy(&v, fb + (size_t)pi * CC + (col - 3), 16);
        } else {
            #pragma unroll
            for (int jj = 0; jj < 4; ++jj) {
                const int gg    = col + jj;
                const int cross = (gg >= OUT_ROW) ? 1 : 0;
                const int rl2   = rl + cross;
                const int c2    = gg - cross * OUT_ROW;
                const int pi2   = s_idx[rl2 < SS ? rl2 : SS - 1];
                v[jj] = (c2 < 3) ? pb[pi2 * 3 + c2]
                                 : fb[(size_t)pi2 * CC + (c2 - 3)];
            }
        }
        __builtin_nontemporal_store(v, oq + e4);
    }
}

extern "C" void kernel_launch(void* const* d_in, const int* in_sizes, int n_in,
                              void* d_out, int out_size, void* d_ws, size_t ws_size,
                              hipStream_t stream) {
    const float* points = (const float*)d_in[0];
    const float* feats  = (const float*)d_in[1];
    const float* boxes  = (const float*)d_in[2];
    float* out_feat = (float*)d_out;
    float* out_flag = (float*)d_out + (size_t)BB * MM * SS * OUT_ROW;

    roipool_fused<<<BB * MM, 1024, 0, stream>>>(points, feats, boxes,
                                                out_feat, out_flag);
}